// Round 15
// baseline (107.741 us; speedup 1.0000x reference)
//
#include <hip/hip_runtime.h>
#include <stdint.h>

#define DIM 128
#define CAP 32

typedef __attribute__((ext_vector_type(8))) short short8;
typedef __attribute__((ext_vector_type(4))) float f32x4;
typedef __attribute__((ext_vector_type(4))) uint32_t u32x4;

static __device__ __forceinline__ uint16_t f2bf(float f) {
  uint32_t u = __builtin_bit_cast(uint32_t, f);
  uint32_t r = (u + 0x7fffu + ((u >> 16) & 1u)) >> 16;  // RNE
  return (uint16_t)r;
}
static __device__ __forceinline__ uint32_t pack2(float a, float b) {
  return (uint32_t)f2bf(a) | ((uint32_t)f2bf(b) << 16);
}
static __device__ __forceinline__ float bflo(uint32_t u) {
  return __builtin_bit_cast(float, (uint32_t)(u << 16));
}
static __device__ __forceinline__ float bfhi(uint32_t u) {
  return __builtin_bit_cast(float, (uint32_t)(u & 0xffff0000u));
}

// ---- inline-asm memory primitives (named regs can't be sunk to scratch) ----
#define GLD4(dstv, ptr) \
  asm volatile("global_load_dwordx4 %0, %1, off" : "=&v"(dstv) : "v"(ptr))
#define VMWAIT(N)                                          \
  asm volatile("s_waitcnt vmcnt(" #N ")" ::: "memory");    \
  __builtin_amdgcn_sched_barrier(0)

// conv worker: x[f32] -> x16[bf16]. UNIT-STRIDE (each load instruction is
// lane-consecutive 16B -> single-touch cachelines) AND asm-forced depth-4
// (4 independent GLD4 in flight per thread; named asm outputs can't be
// collapsed to depth-1 like r12/r14's compiler version, VGPR=8 proof).
static __device__ __forceinline__ void conv_range(
    const float* __restrict__ x, uint32_t* __restrict__ x16,
    int n4, int t, int S) {
  const float4* xp = reinterpret_cast<const float4*>(x);
  uint2* op = reinterpret_cast<uint2*>(x16);
  for (int i0 = t; i0 < n4; i0 += 4 * S) {
    const int i1 = i0 + S, i2 = i0 + 2 * S, i3 = i0 + 3 * S;
    const int c1 = (i1 < n4) ? i1 : i0;
    const int c2 = (i2 < n4) ? i2 : i0;
    const int c3 = (i3 < n4) ? i3 : i0;
    f32x4 L0, L1, L2, L3;
    GLD4(L0, xp + i0);
    GLD4(L1, xp + c1);
    GLD4(L2, xp + c2);
    GLD4(L3, xp + c3);
    VMWAIT(0);
    {
      uint2 o; o.x = pack2(L0[0], L0[1]); o.y = pack2(L0[2], L0[3]);
      op[i0] = o;
    }
    if (i1 < n4) {
      uint2 o; o.x = pack2(L1[0], L1[1]); o.y = pack2(L1[2], L1[3]);
      op[i1] = o;
    }
    if (i2 < n4) {
      uint2 o; o.x = pack2(L2[0], L2[1]); o.y = pack2(L2[2], L2[3]);
      op[i2] = o;
    }
    if (i3 < n4) {
      uint2 o; o.x = pack2(L3[0], L3[1]); o.y = pack2(L3[2], L3[3]);
      op[i3] = o;
    }
  }
}

// ---- K1: conv (blocks [0,convb)) ∥ bucket scatter + B-table ----------------
__global__ __launch_bounds__(256) void k1_conv_bucket(
    const float* __restrict__ x, uint32_t* __restrict__ x16, int n4, int convb,
    const int* __restrict__ src, const int* __restrict__ dst,
    int* __restrict__ cnt, int* __restrict__ bucket, int n_edge,
    const float* __restrict__ W1, const float* __restrict__ W2,
    uint32_t* __restrict__ b_tab) {
  if ((int)blockIdx.x < convb) {
    conv_range(x, x16, n4, blockIdx.x * 256 + threadIdx.x, convb * 256);
    return;
  }
  const int gid = ((int)blockIdx.x - convb) * 256 + threadIdx.x;
  if (gid < 16384) {
    // frag(kst,ct): lane ln, elems j,j+1 -> B[k=kst*32+(ln>>4)*8+j][c=ct*16+(ln&15)]
    const int e = gid << 1;
    const int kst = e >> 12;
    const int ct  = (e >> 9) & 7;
    const int ln  = (e >> 3) & 63;
    const int j   = e & 7;
    const int k   = kst * 32 + ((ln >> 4) << 3) + j;
    const int c   = ct * 16 + (ln & 15);
    const float* wp = (k < 128) ? (W1 + c * 128 + k) : (W2 + c * 128 + (k - 128));
    b_tab[gid] = pack2(wp[0], wp[1]);
  }
  if (gid < n_edge) {
    const int d = dst[gid];
    const int c = atomicAdd(&cnt[d], 1);
    if (c < CAP) bucket[(size_t)d * CAP + c] = src[gid];
  }
}

// Per-edge id lookup from preloaded bucket registers. j is group-uniform.
#define EDGE_SID(J, OUT)                                                    \
  {                                                                         \
    const int _j = (J);                                                     \
    const int _rr = (_j >= b1) + (_j >= b2) + (_j >= b3);                   \
    const int _bs = (_rr == 0) ? 0 : (_rr == 1) ? b1 : (_rr == 2) ? b2 : b3;\
    const int _s = _j - _bs;                                                \
    const int _hi = _s >> 4;                                                \
    const int _v = (_rr == 0) ? (_hi ? idB0 : idA0)                         \
                 : (_rr == 1) ? (_hi ? idB1 : idA1)                         \
                 : (_rr == 2) ? (_hi ? idB2 : idA2)                         \
                 : (_hi ? idB3 : idA3);                                     \
    const int _sid = __shfl(_v, g16 + (_s & 15));                           \
    OUT = (_j < P) ? _sid : 0;                                              \
  }

// ---------------- Fused aggregate + GEMM, bf16 gather, bucket CSR -----------
__global__ __launch_bounds__(256, 4) void fused_bf16_kernel(
    const uint16_t* __restrict__ x16, const int* __restrict__ cnt,
    const int* __restrict__ bucket, const float* __restrict__ degree,
    const int* __restrict__ self_ids, const uint32_t* __restrict__ b_tab,
    float* __restrict__ out, int n_dst)
{
  __shared__ uint32_t As[4][16][132];   // per-wave tiles, stride 528B
  const int tid = threadIdx.x;
  const int w = tid >> 6, lane = tid & 63;
  const int g = lane >> 4, li = lane & 15;
  const int g16 = g << 4, g4 = g << 2, li8 = li << 3;
  const int rbase = blockIdx.x * 64 + w * 16;

  int cnt_all = 0, sid_all = 0;
  float deg_all = 1.f;
  if (lane < 16) {
    const int r = rbase + lane;
    const int rc = (r < n_dst) ? r : 0;
    sid_all = self_ids[rc];
    deg_all = degree[rc];
    int c = cnt[rc];
    c = c > CAP ? CAP : c;
    cnt_all = (r < n_dst) ? c : 0;
  }
  const int c0 = __shfl(cnt_all, g4 + 0);
  const int c1 = __shfl(cnt_all, g4 + 1);
  const int c2 = __shfl(cnt_all, g4 + 2);
  const int c3 = __shfl(cnt_all, g4 + 3);
  const int b1 = c0, b2 = c0 + c1, b3 = b2 + c2;
  const int P = b3 + c3;
  const float inv0 = 1.0f / __shfl(deg_all, g4 + 0);
  const float inv1 = 1.0f / __shfl(deg_all, g4 + 1);
  const float inv2 = 1.0f / __shfl(deg_all, g4 + 2);
  const float inv3 = 1.0f / __shfl(deg_all, g4 + 3);
  const int sid0 = __shfl(sid_all, g4 + 0);
  const int sid1 = __shfl(sid_all, g4 + 1);
  const int sid2 = __shfl(sid_all, g4 + 2);
  const int sid3 = __shfl(sid_all, g4 + 3);

  const int r0c = (rbase + g4 + 0 < n_dst) ? rbase + g4 + 0 : 0;
  const int r1c = (rbase + g4 + 1 < n_dst) ? rbase + g4 + 1 : 0;
  const int r2c = (rbase + g4 + 2 < n_dst) ? rbase + g4 + 2 : 0;
  const int r3c = (rbase + g4 + 3 < n_dst) ? rbase + g4 + 3 : 0;
  const int idA0 = bucket[(size_t)r0c * CAP + li];
  const int idA1 = bucket[(size_t)r1c * CAP + li];
  const int idA2 = bucket[(size_t)r2c * CAP + li];
  const int idA3 = bucket[(size_t)r3c * CAP + li];
  const int idB0 = (c0 > 16) ? bucket[(size_t)r0c * CAP + 16 + li] : 0;
  const int idB1 = (c1 > 16) ? bucket[(size_t)r1c * CAP + 16 + li] : 0;
  const int idB2 = (c2 > 16) ? bucket[(size_t)r2c * CAP + 16 + li] : 0;
  const int idB3 = (c3 > 16) ? bucket[(size_t)r3c * CAP + 16 + li] : 0;

  float a0 = 0.f, a1 = 0.f, a2 = 0.f, a3 = 0.f;
  float a4 = 0.f, a5 = 0.f, a6 = 0.f, a7 = 0.f;
  int rcur = 0;

#define FLUSH1                                                              \
  {                                                                         \
    const float _iv = (rcur == 0) ? inv0 : (rcur == 1) ? inv1               \
                    : (rcur == 2) ? inv2 : inv3;                            \
    uint4 _pa;                                                              \
    _pa.x = pack2(a0 * _iv, a1 * _iv);                                      \
    _pa.y = pack2(a2 * _iv, a3 * _iv);                                      \
    _pa.z = pack2(a4 * _iv, a5 * _iv);                                      \
    _pa.w = pack2(a6 * _iv, a7 * _iv);                                      \
    *reinterpret_cast<uint4*>(&As[w][g4 + rcur][li * 4]) = _pa;             \
    a0 = a1 = a2 = a3 = a4 = a5 = a6 = a7 = 0.f;                            \
    ++rcur;                                                                 \
  }

#define ISSUE4E(Va, Vb, Vc, Vd, E0)                                         \
  {                                                                         \
    int _sa, _sb, _sc, _sd;                                                 \
    EDGE_SID((E0) + 0, _sa);                                                \
    EDGE_SID((E0) + 1, _sb);                                                \
    EDGE_SID((E0) + 2, _sc);                                                \
    EDGE_SID((E0) + 3, _sd);                                                \
    GLD4(Va, x16 + (size_t)_sa * DIM + li8);                                \
    GLD4(Vb, x16 + (size_t)_sb * DIM + li8);                                \
    GLD4(Vc, x16 + (size_t)_sc * DIM + li8);                                \
    GLD4(Vd, x16 + (size_t)_sd * DIM + li8);                                \
  }

#define CONSUME1(V, J)                                                      \
  if ((J) < P) {                                                            \
    while (rcur < 3 &&                                                      \
           (J) >= ((rcur == 0) ? b1 : (rcur == 1) ? b2 : b3)) FLUSH1;       \
    a0 += bflo(V[0]); a1 += bfhi(V[0]);                                     \
    a2 += bflo(V[1]); a3 += bfhi(V[1]);                                     \
    a4 += bflo(V[2]); a5 += bfhi(V[2]);                                     \
    a6 += bflo(V[3]); a7 += bfhi(V[3]);                                     \
  }

  {
    u32x4 A0, A1, A2, A3, B0, B1, B2, B3;
    if (P > 0) {
      ISSUE4E(A0, A1, A2, A3, 0);
      int q = 0;
      for (;;) {
        if (q + 4 < P) {
          ISSUE4E(B0, B1, B2, B3, q + 4);
          VMWAIT(4);
        } else {
          VMWAIT(0);
        }
        CONSUME1(A0, q);
        CONSUME1(A1, q + 1);
        CONSUME1(A2, q + 2);
        CONSUME1(A3, q + 3);
        q += 4;
        if (q >= P) break;
        if (q + 4 < P) {
          ISSUE4E(A0, A1, A2, A3, q + 4);
          VMWAIT(4);
        } else {
          VMWAIT(0);
        }
        CONSUME1(B0, q);
        CONSUME1(B1, q + 1);
        CONSUME1(B2, q + 2);
        CONSUME1(B3, q + 3);
        q += 4;
        if (q >= P) break;
      }
    }
    while (rcur < 4) FLUSH1;
  }

  // Self rows (K=128..255): x16 already bf16 -> direct copy.
  {
    const uint4 sv0 = *reinterpret_cast<const uint4*>(x16 + (size_t)sid0 * DIM + li8);
    const uint4 sv1 = *reinterpret_cast<const uint4*>(x16 + (size_t)sid1 * DIM + li8);
    const uint4 sv2 = *reinterpret_cast<const uint4*>(x16 + (size_t)sid2 * DIM + li8);
    const uint4 sv3 = *reinterpret_cast<const uint4*>(x16 + (size_t)sid3 * DIM + li8);
    *reinterpret_cast<uint4*>(&As[w][g4 + 0][64 + li * 4]) = sv0;
    *reinterpret_cast<uint4*>(&As[w][g4 + 1][64 + li * 4]) = sv1;
    *reinterpret_cast<uint4*>(&As[w][g4 + 2][64 + li * 4]) = sv2;
    *reinterpret_cast<uint4*>(&As[w][g4 + 3][64 + li * 4]) = sv3;
  }

  // Phase B: A-frag lane ln holds A[row=ln&15][k=kst*32+(ln>>4)*8+j], j=0..7.
  const uint32_t* Arow = &As[w][lane & 15][(lane >> 4) << 2];
  const uint16_t* Bt = (const uint16_t*)b_tab;
  f32x4 acc[8] = {};
#pragma unroll
  for (int kst = 0; kst < 8; ++kst) {
    const short8 av = *reinterpret_cast<const short8*>(Arow + kst * 16);
#pragma unroll
    for (int ct = 0; ct < 8; ++ct) {
      const short8 bv = *reinterpret_cast<const short8*>(Bt + (kst * 8 + ct) * 512 + lane * 8);
      acc[ct] = __builtin_amdgcn_mfma_f32_16x16x32_bf16(av, bv, acc[ct], 0, 0, 0);
    }
  }

  // C/D (m89): col = lane&15, row = (lane>>4)*4 + reg.
  const int rout = rbase + ((lane >> 4) << 2);
  const int ccol = lane & 15;
#pragma unroll
  for (int ct = 0; ct < 8; ++ct) {
#pragma unroll
    for (int j = 0; j < 4; ++j) {
      const int row = rout + j;
      if (row < n_dst) out[(size_t)row * DIM + ct * 16 + ccol] = acc[ct][j];
    }
  }
#undef FLUSH1
#undef ISSUE4E
#undef CONSUME1
}

// ---------------- Fallback: f32 gather, bucket CSR (ws too small for x16) ---
__global__ __launch_bounds__(256, 4) void fused_f32_kernel(
    const float* __restrict__ x, const int* __restrict__ cnt,
    const int* __restrict__ bucket, const float* __restrict__ degree,
    const int* __restrict__ self_ids, const uint32_t* __restrict__ b_tab,
    float* __restrict__ out, int n_dst)
{
  __shared__ uint32_t As[4][16][132];
  const int tid = threadIdx.x;
  const int w = tid >> 6, lane = tid & 63;
  const int g = lane >> 4, li = lane & 15;
  const int g16 = g << 4, g4 = g << 2, li8 = li << 3;
  const int rbase = blockIdx.x * 64 + w * 16;

  int cnt_all = 0, sid_all = 0;
  float deg_all = 1.f;
  if (lane < 16) {
    const int r = rbase + lane;
    const int rc = (r < n_dst) ? r : 0;
    sid_all = self_ids[rc];
    deg_all = degree[rc];
    int c = cnt[rc];
    c = c > CAP ? CAP : c;
    cnt_all = (r < n_dst) ? c : 0;
  }
  const int c0 = __shfl(cnt_all, g4 + 0);
  const int c1 = __shfl(cnt_all, g4 + 1);
  const int c2 = __shfl(cnt_all, g4 + 2);
  const int c3 = __shfl(cnt_all, g4 + 3);
  const int b1 = c0, b2 = c0 + c1, b3 = b2 + c2;
  const int P = b3 + c3;
  const float inv0 = 1.0f / __shfl(deg_all, g4 + 0);
  const float inv1 = 1.0f / __shfl(deg_all, g4 + 1);
  const float inv2 = 1.0f / __shfl(deg_all, g4 + 2);
  const float inv3 = 1.0f / __shfl(deg_all, g4 + 3);
  const int sid0 = __shfl(sid_all, g4 + 0);
  const int sid1 = __shfl(sid_all, g4 + 1);
  const int sid2 = __shfl(sid_all, g4 + 2);
  const int sid3 = __shfl(sid_all, g4 + 3);

  const int r0c = (rbase + g4 + 0 < n_dst) ? rbase + g4 + 0 : 0;
  const int r1c = (rbase + g4 + 1 < n_dst) ? rbase + g4 + 1 : 0;
  const int r2c = (rbase + g4 + 2 < n_dst) ? rbase + g4 + 2 : 0;
  const int r3c = (rbase + g4 + 3 < n_dst) ? rbase + g4 + 3 : 0;
  const int idA0 = bucket[(size_t)r0c * CAP + li];
  const int idA1 = bucket[(size_t)r1c * CAP + li];
  const int idA2 = bucket[(size_t)r2c * CAP + li];
  const int idA3 = bucket[(size_t)r3c * CAP + li];
  const int idB0 = (c0 > 16) ? bucket[(size_t)r0c * CAP + 16 + li] : 0;
  const int idB1 = (c1 > 16) ? bucket[(size_t)r1c * CAP + 16 + li] : 0;
  const int idB2 = (c2 > 16) ? bucket[(size_t)r2c * CAP + 16 + li] : 0;
  const int idB3 = (c3 > 16) ? bucket[(size_t)r3c * CAP + 16 + li] : 0;

  float a0 = 0.f, a1 = 0.f, a2 = 0.f, a3 = 0.f;
  float a4 = 0.f, a5 = 0.f, a6 = 0.f, a7 = 0.f;
  int rcur = 0;

#define FLUSH1F                                                             \
  {                                                                         \
    const float _iv = (rcur == 0) ? inv0 : (rcur == 1) ? inv1               \
                    : (rcur == 2) ? inv2 : inv3;                            \
    uint4 _pa;                                                              \
    _pa.x = pack2(a0 * _iv, a1 * _iv);                                      \
    _pa.y = pack2(a2 * _iv, a3 * _iv);                                      \
    _pa.z = pack2(a4 * _iv, a5 * _iv);                                      \
    _pa.w = pack2(a6 * _iv, a7 * _iv);                                      \
    *reinterpret_cast<uint4*>(&As[w][g4 + rcur][li * 4]) = _pa;             \
    a0 = a1 = a2 = a3 = a4 = a5 = a6 = a7 = 0.f;                            \
    ++rcur;                                                                 \
  }

#define ISSUE2F(Va, Vb, Vc, Vd, E0)                                         \
  {                                                                         \
    int _sa, _sb;                                                           \
    EDGE_SID((E0) + 0, _sa);                                                \
    EDGE_SID((E0) + 1, _sb);                                                \
    const float* _p0 = x + (size_t)_sa * DIM + li8;                         \
    const float* _p1 = x + (size_t)_sb * DIM + li8;                         \
    GLD4(Va, _p0); GLD4(Vb, _p0 + 4);                                       \
    GLD4(Vc, _p1); GLD4(Vd, _p1 + 4);                                       \
  }

#define CONSUME_EF(Va, Vb, J)                                               \
  if ((J) < P) {                                                            \
    while (rcur < 3 &&                                                      \
           (J) >= ((rcur == 0) ? b1 : (rcur == 1) ? b2 : b3)) FLUSH1F;      \
    a0 += Va[0]; a1 += Va[1]; a2 += Va[2]; a3 += Va[3];                     \
    a4 += Vb[0]; a5 += Vb[1]; a6 += Vb[2]; a7 += Vb[3];                     \
  }

  {
    f32x4 A0, A1, A2, A3, B0, B1, B2, B3;
    if (P > 0) {
      ISSUE2F(A0, A1, A2, A3, 0);
      int q = 0;
      for (;;) {
        if (q + 2 < P) {
          ISSUE2F(B0, B1, B2, B3, q + 2);
          VMWAIT(4);
        } else {
          VMWAIT(0);
        }
        CONSUME_EF(A0, A1, q);
        CONSUME_EF(A2, A3, q + 1);
        q += 2;
        if (q >= P) break;
        if (q + 2 < P) {
          ISSUE2F(A0, A1, A2, A3, q + 2);
          VMWAIT(4);
        } else {
          VMWAIT(0);
        }
        CONSUME_EF(B0, B1, q);
        CONSUME_EF(B2, B3, q + 1);
        q += 2;
        if (q >= P) break;
      }
    }
    while (rcur < 4) FLUSH1F;
  }

  {
    const int sids[4] = {sid0, sid1, sid2, sid3};
#pragma unroll
    for (int r = 0; r < 4; ++r) {
      const float4* xs = reinterpret_cast<const float4*>(x + (size_t)sids[r] * DIM + li8);
      const float4 t0 = xs[0], t1 = xs[1];
      uint4 ps;
      ps.x = pack2(t0.x, t0.y);
      ps.y = pack2(t0.z, t0.w);
      ps.z = pack2(t1.x, t1.y);
      ps.w = pack2(t1.z, t1.w);
      *reinterpret_cast<uint4*>(&As[w][g4 + r][64 + li * 4]) = ps;
    }
  }

  const uint32_t* Arow = &As[w][lane & 15][(lane >> 4) << 2];
  const uint16_t* Bt = (const uint16_t*)b_tab;
  f32x4 acc[8] = {};
#pragma unroll
  for (int kst = 0; kst < 8; ++kst) {
    const short8 av = *reinterpret_cast<const short8*>(Arow + kst * 16);
#pragma unroll
    for (int ct = 0; ct < 8; ++ct) {
      const short8 bv = *reinterpret_cast<const short8*>(Bt + (kst * 8 + ct) * 512 + lane * 8);
      acc[ct] = __builtin_amdgcn_mfma_f32_16x16x32_bf16(av, bv, acc[ct], 0, 0, 0);
    }
  }

  const int rout = rbase + ((lane >> 4) << 2);
  const int ccol = lane & 15;
#pragma unroll
  for (int ct = 0; ct < 8; ++ct) {
#pragma unroll
    for (int j = 0; j < 4; ++j) {
      const int row = rout + j;
      if (row < n_dst) out[(size_t)row * DIM + ct * 16 + ccol] = acc[ct][j];
    }
  }
#undef FLUSH1F
#undef ISSUE2F
#undef CONSUME_EF
}

extern "C" void kernel_launch(void* const* d_in, const int* in_sizes, int n_in,
                              void* d_out, int out_size, void* d_ws, size_t ws_size,
                              hipStream_t stream) {
  const float* x        = (const float*)d_in[0];
  const float* W1       = (const float*)d_in[1];
  const float* W2       = (const float*)d_in[2];
  const float* degree   = (const float*)d_in[3];
  const int*   src_idx  = (const int*)d_in[4];
  const int*   dst_idx  = (const int*)d_in[5];
  const int*   self_ids = (const int*)d_in[6];
  float* out = (float*)d_out;
  const int n_dst  = in_sizes[3];
  const int n_edge = in_sizes[4];
  const int n_src  = in_sizes[0] / DIM;

  // ws: cnt | b_tab | bucket(n_dst*CAP) | x16(51MB, optional)
  auto align256 = [](size_t v) { return (v + 255) & ~(size_t)255; };
  char* ws = (char*)d_ws;
  size_t o_cnt    = 0;
  size_t o_btab   = align256(o_cnt + (size_t)n_dst * 4);
  size_t o_bucket = align256(o_btab + 16384 * 4);
  size_t o_x16    = align256(o_bucket + (size_t)n_dst * CAP * 4);
  const size_t x16_bytes = (size_t)n_src * DIM * 2;
  int* cnt    = (int*)(ws + o_cnt);
  uint32_t* b_tab = (uint32_t*)(ws + o_btab);
  int* bucket = (int*)(ws + o_bucket);
  uint32_t* x16 = (uint32_t*)(ws + o_x16);

  const bool use_bf16 = (ws_size >= o_x16 + x16_bytes);
  const int n4 = use_bf16 ? n_src * (DIM / 4) : 0;  // float4 units to convert

  const int convb = use_bf16 ? 2048 : 0;
  int bucketb = (n_edge + 255) / 256;
  if (bucketb < 64) bucketb = 64;  // ensure b_tab (16384 threads) covered

  hipMemsetAsync(cnt, 0, (size_t)n_dst * 4, stream);
  k1_conv_bucket<<<convb + bucketb, 256, 0, stream>>>(
      x, x16, n4, convb, src_idx, dst_idx, cnt, bucket, n_edge, W1, W2, b_tab);
  if (use_bf16) {
    fused_bf16_kernel<<<(n_dst + 63) / 64, 256, 0, stream>>>(
        (const uint16_t*)x16, cnt, bucket, degree, self_ids, b_tab, out, n_dst);
  } else {
    fused_f32_kernel<<<(n_dst + 63) / 64, 256, 0, stream>>>(
        x, cnt, bucket, degree, self_ids, b_tab, out, n_dst);
  }
}

// Round 16
// 103.035 us; speedup vs baseline: 1.0457x; 1.0457x over previous
//
#include <hip/hip_runtime.h>
#include <stdint.h>

#define DIM 128
#define CAP 32

typedef __attribute__((ext_vector_type(8))) short short8;
typedef __attribute__((ext_vector_type(4))) float f32x4;
typedef __attribute__((ext_vector_type(4))) uint32_t u32x4;

static __device__ __forceinline__ uint16_t f2bf(float f) {
  uint32_t u = __builtin_bit_cast(uint32_t, f);
  uint32_t r = (u + 0x7fffu + ((u >> 16) & 1u)) >> 16;  // RNE
  return (uint16_t)r;
}
static __device__ __forceinline__ uint32_t pack2(float a, float b) {
  return (uint32_t)f2bf(a) | ((uint32_t)f2bf(b) << 16);
}
static __device__ __forceinline__ float bflo(uint32_t u) {
  return __builtin_bit_cast(float, (uint32_t)(u << 16));
}
static __device__ __forceinline__ float bfhi(uint32_t u) {
  return __builtin_bit_cast(float, (uint32_t)(u & 0xffff0000u));
}

// ---- inline-asm memory primitives (named regs can't be sunk to scratch) ----
#define GLD4(dstv, ptr) \
  asm volatile("global_load_dwordx4 %0, %1, off" : "=&v"(dstv) : "v"(ptr))
#define VMWAIT(N)                                          \
  asm volatile("s_waitcnt vmcnt(" #N ")" ::: "memory");    \
  __builtin_amdgcn_sched_barrier(0)

// conv worker: x[f32] -> x16[bf16]. Unit-stride loads, asm-forced depth-4,
// counted VMWAIT(3) ladder: each wait retires exactly the load the next
// store needs; remaining loads + issued stores stay in flight, and the next
// iteration's loads issue while this iteration's stores are outstanding.
static __device__ __forceinline__ void conv_range(
    const float* __restrict__ x, uint32_t* __restrict__ x16,
    int n4, int t, int S) {
  const float4* xp = reinterpret_cast<const float4*>(x);
  uint2* op = reinterpret_cast<uint2*>(x16);
  for (int i0 = t; i0 < n4; i0 += 4 * S) {
    const int i1 = i0 + S, i2 = i0 + 2 * S, i3 = i0 + 3 * S;
    const int c1 = (i1 < n4) ? i1 : i0;
    const int c2 = (i2 < n4) ? i2 : i0;
    const int c3 = (i3 < n4) ? i3 : i0;
    f32x4 L0, L1, L2, L3;
    GLD4(L0, xp + i0);
    GLD4(L1, xp + c1);
    GLD4(L2, xp + c2);
    GLD4(L3, xp + c3);
    VMWAIT(3);
    {
      uint2 o; o.x = pack2(L0[0], L0[1]); o.y = pack2(L0[2], L0[3]);
      op[i0] = o;
    }
    VMWAIT(3);
    if (i1 < n4) {
      uint2 o; o.x = pack2(L1[0], L1[1]); o.y = pack2(L1[2], L1[3]);
      op[i1] = o;
    }
    VMWAIT(3);
    if (i2 < n4) {
      uint2 o; o.x = pack2(L2[0], L2[1]); o.y = pack2(L2[2], L2[3]);
      op[i2] = o;
    }
    VMWAIT(3);
    if (i3 < n4) {
      uint2 o; o.x = pack2(L3[0], L3[1]); o.y = pack2(L3[2], L3[3]);
      op[i3] = o;
    }
  }
}

// ---- K1: conv (blocks [0,convb)) ∥ bucket scatter + B-table ----------------
__global__ __launch_bounds__(256) void k1_conv_bucket(
    const float* __restrict__ x, uint32_t* __restrict__ x16, int n4, int convb,
    const int* __restrict__ src, const int* __restrict__ dst,
    int* __restrict__ cnt, int* __restrict__ bucket, int n_edge,
    const float* __restrict__ W1, const float* __restrict__ W2,
    uint32_t* __restrict__ b_tab) {
  if ((int)blockIdx.x < convb) {
    conv_range(x, x16, n4, blockIdx.x * 256 + threadIdx.x, convb * 256);
    return;
  }
  const int gid = ((int)blockIdx.x - convb) * 256 + threadIdx.x;
  if (gid < 16384) {
    // frag(kst,ct): lane ln, elems j,j+1 -> B[k=kst*32+(ln>>4)*8+j][c=ct*16+(ln&15)]
    const int e = gid << 1;
    const int kst = e >> 12;
    const int ct  = (e >> 9) & 7;
    const int ln  = (e >> 3) & 63;
    const int j   = e & 7;
    const int k   = kst * 32 + ((ln >> 4) << 3) + j;
    const int c   = ct * 16 + (ln & 15);
    const float* wp = (k < 128) ? (W1 + c * 128 + k) : (W2 + c * 128 + (k - 128));
    b_tab[gid] = pack2(wp[0], wp[1]);
  }
  if (gid < n_edge) {
    const int d = dst[gid];
    const int c = atomicAdd(&cnt[d], 1);
    if (c < CAP) bucket[(size_t)d * CAP + c] = src[gid];
  }
}

// Per-edge id lookup from preloaded bucket registers. j is group-uniform.
#define EDGE_SID(J, OUT)                                                    \
  {                                                                         \
    const int _j = (J);                                                     \
    const int _rr = (_j >= b1) + (_j >= b2) + (_j >= b3);                   \
    const int _bs = (_rr == 0) ? 0 : (_rr == 1) ? b1 : (_rr == 2) ? b2 : b3;\
    const int _s = _j - _bs;                                                \
    const int _hi = _s >> 4;                                                \
    const int _v = (_rr == 0) ? (_hi ? idB0 : idA0)                         \
                 : (_rr == 1) ? (_hi ? idB1 : idA1)                         \
                 : (_rr == 2) ? (_hi ? idB2 : idA2)                         \
                 : (_hi ? idB3 : idA3);                                     \
    const int _sid = __shfl(_v, g16 + (_s & 15));                           \
    OUT = (_j < P) ? _sid : 0;                                              \
  }

// ---------------- Fused aggregate + GEMM, bf16 gather, bucket CSR -----------
__global__ __launch_bounds__(256, 4) void fused_bf16_kernel(
    const uint16_t* __restrict__ x16, const int* __restrict__ cnt,
    const int* __restrict__ bucket, const float* __restrict__ degree,
    const int* __restrict__ self_ids, const uint32_t* __restrict__ b_tab,
    float* __restrict__ out, int n_dst)
{
  __shared__ uint32_t As[4][16][132];   // per-wave tiles, stride 528B
  const int tid = threadIdx.x;
  const int w = tid >> 6, lane = tid & 63;
  const int g = lane >> 4, li = lane & 15;
  const int g16 = g << 4, g4 = g << 2, li8 = li << 3;
  const int rbase = blockIdx.x * 64 + w * 16;

  int cnt_all = 0, sid_all = 0;
  float deg_all = 1.f;
  if (lane < 16) {
    const int r = rbase + lane;
    const int rc = (r < n_dst) ? r : 0;
    sid_all = self_ids[rc];
    deg_all = degree[rc];
    int c = cnt[rc];
    c = c > CAP ? CAP : c;
    cnt_all = (r < n_dst) ? c : 0;
  }
  const int c0 = __shfl(cnt_all, g4 + 0);
  const int c1 = __shfl(cnt_all, g4 + 1);
  const int c2 = __shfl(cnt_all, g4 + 2);
  const int c3 = __shfl(cnt_all, g4 + 3);
  const int b1 = c0, b2 = c0 + c1, b3 = b2 + c2;
  const int P = b3 + c3;
  const float inv0 = 1.0f / __shfl(deg_all, g4 + 0);
  const float inv1 = 1.0f / __shfl(deg_all, g4 + 1);
  const float inv2 = 1.0f / __shfl(deg_all, g4 + 2);
  const float inv3 = 1.0f / __shfl(deg_all, g4 + 3);
  const int sid0 = __shfl(sid_all, g4 + 0);
  const int sid1 = __shfl(sid_all, g4 + 1);
  const int sid2 = __shfl(sid_all, g4 + 2);
  const int sid3 = __shfl(sid_all, g4 + 3);

  const int r0c = (rbase + g4 + 0 < n_dst) ? rbase + g4 + 0 : 0;
  const int r1c = (rbase + g4 + 1 < n_dst) ? rbase + g4 + 1 : 0;
  const int r2c = (rbase + g4 + 2 < n_dst) ? rbase + g4 + 2 : 0;
  const int r3c = (rbase + g4 + 3 < n_dst) ? rbase + g4 + 3 : 0;
  const int idA0 = bucket[(size_t)r0c * CAP + li];
  const int idA1 = bucket[(size_t)r1c * CAP + li];
  const int idA2 = bucket[(size_t)r2c * CAP + li];
  const int idA3 = bucket[(size_t)r3c * CAP + li];
  const int idB0 = (c0 > 16) ? bucket[(size_t)r0c * CAP + 16 + li] : 0;
  const int idB1 = (c1 > 16) ? bucket[(size_t)r1c * CAP + 16 + li] : 0;
  const int idB2 = (c2 > 16) ? bucket[(size_t)r2c * CAP + 16 + li] : 0;
  const int idB3 = (c3 > 16) ? bucket[(size_t)r3c * CAP + 16 + li] : 0;

  float a0 = 0.f, a1 = 0.f, a2 = 0.f, a3 = 0.f;
  float a4 = 0.f, a5 = 0.f, a6 = 0.f, a7 = 0.f;
  int rcur = 0;

#define FLUSH1                                                              \
  {                                                                         \
    const float _iv = (rcur == 0) ? inv0 : (rcur == 1) ? inv1               \
                    : (rcur == 2) ? inv2 : inv3;                            \
    uint4 _pa;                                                              \
    _pa.x = pack2(a0 * _iv, a1 * _iv);                                      \
    _pa.y = pack2(a2 * _iv, a3 * _iv);                                      \
    _pa.z = pack2(a4 * _iv, a5 * _iv);                                      \
    _pa.w = pack2(a6 * _iv, a7 * _iv);                                      \
    *reinterpret_cast<uint4*>(&As[w][g4 + rcur][li * 4]) = _pa;             \
    a0 = a1 = a2 = a3 = a4 = a5 = a6 = a7 = 0.f;                            \
    ++rcur;                                                                 \
  }

#define ISSUE4E(Va, Vb, Vc, Vd, E0)                                         \
  {                                                                         \
    int _sa, _sb, _sc, _sd;                                                 \
    EDGE_SID((E0) + 0, _sa);                                                \
    EDGE_SID((E0) + 1, _sb);                                                \
    EDGE_SID((E0) + 2, _sc);                                                \
    EDGE_SID((E0) + 3, _sd);                                                \
    GLD4(Va, x16 + (size_t)_sa * DIM + li8);                                \
    GLD4(Vb, x16 + (size_t)_sb * DIM + li8);                                \
    GLD4(Vc, x16 + (size_t)_sc * DIM + li8);                                \
    GLD4(Vd, x16 + (size_t)_sd * DIM + li8);                                \
  }

#define CONSUME1(V, J)                                                      \
  if ((J) < P) {                                                            \
    while (rcur < 3 &&                                                      \
           (J) >= ((rcur == 0) ? b1 : (rcur == 1) ? b2 : b3)) FLUSH1;       \
    a0 += bflo(V[0]); a1 += bfhi(V[0]);                                     \
    a2 += bflo(V[1]); a3 += bfhi(V[1]);                                     \
    a4 += bflo(V[2]); a5 += bfhi(V[2]);                                     \
    a6 += bflo(V[3]); a7 += bfhi(V[3]);                                     \
  }

  {
    u32x4 A0, A1, A2, A3, B0, B1, B2, B3;
    if (P > 0) {
      ISSUE4E(A0, A1, A2, A3, 0);
      int q = 0;
      for (;;) {
        if (q + 4 < P) {
          ISSUE4E(B0, B1, B2, B3, q + 4);
          VMWAIT(4);
        } else {
          VMWAIT(0);
        }
        CONSUME1(A0, q);
        CONSUME1(A1, q + 1);
        CONSUME1(A2, q + 2);
        CONSUME1(A3, q + 3);
        q += 4;
        if (q >= P) break;
        if (q + 4 < P) {
          ISSUE4E(A0, A1, A2, A3, q + 4);
          VMWAIT(4);
        } else {
          VMWAIT(0);
        }
        CONSUME1(B0, q);
        CONSUME1(B1, q + 1);
        CONSUME1(B2, q + 2);
        CONSUME1(B3, q + 3);
        q += 4;
        if (q >= P) break;
      }
    }
    while (rcur < 4) FLUSH1;
  }

  // Self rows (K=128..255): x16 already bf16 -> direct copy.
  {
    const uint4 sv0 = *reinterpret_cast<const uint4*>(x16 + (size_t)sid0 * DIM + li8);
    const uint4 sv1 = *reinterpret_cast<const uint4*>(x16 + (size_t)sid1 * DIM + li8);
    const uint4 sv2 = *reinterpret_cast<const uint4*>(x16 + (size_t)sid2 * DIM + li8);
    const uint4 sv3 = *reinterpret_cast<const uint4*>(x16 + (size_t)sid3 * DIM + li8);
    *reinterpret_cast<uint4*>(&As[w][g4 + 0][64 + li * 4]) = sv0;
    *reinterpret_cast<uint4*>(&As[w][g4 + 1][64 + li * 4]) = sv1;
    *reinterpret_cast<uint4*>(&As[w][g4 + 2][64 + li * 4]) = sv2;
    *reinterpret_cast<uint4*>(&As[w][g4 + 3][64 + li * 4]) = sv3;
  }

  // Phase B: A-frag lane ln holds A[row=ln&15][k=kst*32+(ln>>4)*8+j], j=0..7.
  const uint32_t* Arow = &As[w][lane & 15][(lane >> 4) << 2];
  const uint16_t* Bt = (const uint16_t*)b_tab;
  f32x4 acc[8] = {};
#pragma unroll
  for (int kst = 0; kst < 8; ++kst) {
    const short8 av = *reinterpret_cast<const short8*>(Arow + kst * 16);
#pragma unroll
    for (int ct = 0; ct < 8; ++ct) {
      const short8 bv = *reinterpret_cast<const short8*>(Bt + (kst * 8 + ct) * 512 + lane * 8);
      acc[ct] = __builtin_amdgcn_mfma_f32_16x16x32_bf16(av, bv, acc[ct], 0, 0, 0);
    }
  }

  // C/D (m89): col = lane&15, row = (lane>>4)*4 + reg.
  const int rout = rbase + ((lane >> 4) << 2);
  const int ccol = lane & 15;
#pragma unroll
  for (int ct = 0; ct < 8; ++ct) {
#pragma unroll
    for (int j = 0; j < 4; ++j) {
      const int row = rout + j;
      if (row < n_dst) out[(size_t)row * DIM + ct * 16 + ccol] = acc[ct][j];
    }
  }
#undef FLUSH1
#undef ISSUE4E
#undef CONSUME1
}

// ---------------- Fallback: f32 gather, bucket CSR (ws too small for x16) ---
__global__ __launch_bounds__(256, 4) void fused_f32_kernel(
    const float* __restrict__ x, const int* __restrict__ cnt,
    const int* __restrict__ bucket, const float* __restrict__ degree,
    const int* __restrict__ self_ids, const uint32_t* __restrict__ b_tab,
    float* __restrict__ out, int n_dst)
{
  __shared__ uint32_t As[4][16][132];
  const int tid = threadIdx.x;
  const int w = tid >> 6, lane = tid & 63;
  const int g = lane >> 4, li = lane & 15;
  const int g16 = g << 4, g4 = g << 2, li8 = li << 3;
  const int rbase = blockIdx.x * 64 + w * 16;

  int cnt_all = 0, sid_all = 0;
  float deg_all = 1.f;
  if (lane < 16) {
    const int r = rbase + lane;
    const int rc = (r < n_dst) ? r : 0;
    sid_all = self_ids[rc];
    deg_all = degree[rc];
    int c = cnt[rc];
    c = c > CAP ? CAP : c;
    cnt_all = (r < n_dst) ? c : 0;
  }
  const int c0 = __shfl(cnt_all, g4 + 0);
  const int c1 = __shfl(cnt_all, g4 + 1);
  const int c2 = __shfl(cnt_all, g4 + 2);
  const int c3 = __shfl(cnt_all, g4 + 3);
  const int b1 = c0, b2 = c0 + c1, b3 = b2 + c2;
  const int P = b3 + c3;
  const float inv0 = 1.0f / __shfl(deg_all, g4 + 0);
  const float inv1 = 1.0f / __shfl(deg_all, g4 + 1);
  const float inv2 = 1.0f / __shfl(deg_all, g4 + 2);
  const float inv3 = 1.0f / __shfl(deg_all, g4 + 3);
  const int sid0 = __shfl(sid_all, g4 + 0);
  const int sid1 = __shfl(sid_all, g4 + 1);
  const int sid2 = __shfl(sid_all, g4 + 2);
  const int sid3 = __shfl(sid_all, g4 + 3);

  const int r0c = (rbase + g4 + 0 < n_dst) ? rbase + g4 + 0 : 0;
  const int r1c = (rbase + g4 + 1 < n_dst) ? rbase + g4 + 1 : 0;
  const int r2c = (rbase + g4 + 2 < n_dst) ? rbase + g4 + 2 : 0;
  const int r3c = (rbase + g4 + 3 < n_dst) ? rbase + g4 + 3 : 0;
  const int idA0 = bucket[(size_t)r0c * CAP + li];
  const int idA1 = bucket[(size_t)r1c * CAP + li];
  const int idA2 = bucket[(size_t)r2c * CAP + li];
  const int idA3 = bucket[(size_t)r3c * CAP + li];
  const int idB0 = (c0 > 16) ? bucket[(size_t)r0c * CAP + 16 + li] : 0;
  const int idB1 = (c1 > 16) ? bucket[(size_t)r1c * CAP + 16 + li] : 0;
  const int idB2 = (c2 > 16) ? bucket[(size_t)r2c * CAP + 16 + li] : 0;
  const int idB3 = (c3 > 16) ? bucket[(size_t)r3c * CAP + 16 + li] : 0;

  float a0 = 0.f, a1 = 0.f, a2 = 0.f, a3 = 0.f;
  float a4 = 0.f, a5 = 0.f, a6 = 0.f, a7 = 0.f;
  int rcur = 0;

#define FLUSH1F                                                             \
  {                                                                         \
    const float _iv = (rcur == 0) ? inv0 : (rcur == 1) ? inv1               \
                    : (rcur == 2) ? inv2 : inv3;                            \
    uint4 _pa;                                                              \
    _pa.x = pack2(a0 * _iv, a1 * _iv);                                      \
    _pa.y = pack2(a2 * _iv, a3 * _iv);                                      \
    _pa.z = pack2(a4 * _iv, a5 * _iv);                                      \
    _pa.w = pack2(a6 * _iv, a7 * _iv);                                      \
    *reinterpret_cast<uint4*>(&As[w][g4 + rcur][li * 4]) = _pa;             \
    a0 = a1 = a2 = a3 = a4 = a5 = a6 = a7 = 0.f;                            \
    ++rcur;                                                                 \
  }

#define ISSUE2F(Va, Vb, Vc, Vd, E0)                                         \
  {                                                                         \
    int _sa, _sb;                                                           \
    EDGE_SID((E0) + 0, _sa);                                                \
    EDGE_SID((E0) + 1, _sb);                                                \
    const float* _p0 = x + (size_t)_sa * DIM + li8;                         \
    const float* _p1 = x + (size_t)_sb * DIM + li8;                         \
    GLD4(Va, _p0); GLD4(Vb, _p0 + 4);                                       \
    GLD4(Vc, _p1); GLD4(Vd, _p1 + 4);                                       \
  }

#define CONSUME_EF(Va, Vb, J)                                               \
  if ((J) < P) {                                                            \
    while (rcur < 3 &&                                                      \
           (J) >= ((rcur == 0) ? b1 : (rcur == 1) ? b2 : b3)) FLUSH1F;      \
    a0 += Va[0]; a1 += Va[1]; a2 += Va[2]; a3 += Va[3];                     \
    a4 += Vb[0]; a5 += Vb[1]; a6 += Vb[2]; a7 += Vb[3];                     \
  }

  {
    f32x4 A0, A1, A2, A3, B0, B1, B2, B3;
    if (P > 0) {
      ISSUE2F(A0, A1, A2, A3, 0);
      int q = 0;
      for (;;) {
        if (q + 2 < P) {
          ISSUE2F(B0, B1, B2, B3, q + 2);
          VMWAIT(4);
        } else {
          VMWAIT(0);
        }
        CONSUME_EF(A0, A1, q);
        CONSUME_EF(A2, A3, q + 1);
        q += 2;
        if (q >= P) break;
        if (q + 2 < P) {
          ISSUE2F(A0, A1, A2, A3, q + 2);
          VMWAIT(4);
        } else {
          VMWAIT(0);
        }
        CONSUME_EF(B0, B1, q);
        CONSUME_EF(B2, B3, q + 1);
        q += 2;
        if (q >= P) break;
      }
    }
    while (rcur < 4) FLUSH1F;
  }

  {
    const int sids[4] = {sid0, sid1, sid2, sid3};
#pragma unroll
    for (int r = 0; r < 4; ++r) {
      const float4* xs = reinterpret_cast<const float4*>(x + (size_t)sids[r] * DIM + li8);
      const float4 t0 = xs[0], t1 = xs[1];
      uint4 ps;
      ps.x = pack2(t0.x, t0.y);
      ps.y = pack2(t0.z, t0.w);
      ps.z = pack2(t1.x, t1.y);
      ps.w = pack2(t1.z, t1.w);
      *reinterpret_cast<uint4*>(&As[w][g4 + r][64 + li * 4]) = ps;
    }
  }

  const uint32_t* Arow = &As[w][lane & 15][(lane >> 4) << 2];
  const uint16_t* Bt = (const uint16_t*)b_tab;
  f32x4 acc[8] = {};
#pragma unroll
  for (int kst = 0; kst < 8; ++kst) {
    const short8 av = *reinterpret_cast<const short8*>(Arow + kst * 16);
#pragma unroll
    for (int ct = 0; ct < 8; ++ct) {
      const short8 bv = *reinterpret_cast<const short8*>(Bt + (kst * 8 + ct) * 512 + lane * 8);
      acc[ct] = __builtin_amdgcn_mfma_f32_16x16x32_bf16(av, bv, acc[ct], 0, 0, 0);
    }
  }

  const int rout = rbase + ((lane >> 4) << 2);
  const int ccol = lane & 15;
#pragma unroll
  for (int ct = 0; ct < 8; ++ct) {
#pragma unroll
    for (int j = 0; j < 4; ++j) {
      const int row = rout + j;
      if (row < n_dst) out[(size_t)row * DIM + ct * 16 + ccol] = acc[ct][j];
    }
  }
#undef FLUSH1F
#undef ISSUE2F
#undef CONSUME_EF
}

extern "C" void kernel_launch(void* const* d_in, const int* in_sizes, int n_in,
                              void* d_out, int out_size, void* d_ws, size_t ws_size,
                              hipStream_t stream) {
  const float* x        = (const float*)d_in[0];
  const float* W1       = (const float*)d_in[1];
  const float* W2       = (const float*)d_in[2];
  const float* degree   = (const float*)d_in[3];
  const int*   src_idx  = (const int*)d_in[4];
  const int*   dst_idx  = (const int*)d_in[5];
  const int*   self_ids = (const int*)d_in[6];
  float* out = (float*)d_out;
  const int n_dst  = in_sizes[3];
  const int n_edge = in_sizes[4];
  const int n_src  = in_sizes[0] / DIM;

  // ws: cnt | b_tab | bucket(n_dst*CAP) | x16(51MB, optional)
  auto align256 = [](size_t v) { return (v + 255) & ~(size_t)255; };
  char* ws = (char*)d_ws;
  size_t o_cnt    = 0;
  size_t o_btab   = align256(o_cnt + (size_t)n_dst * 4);
  size_t o_bucket = align256(o_btab + 16384 * 4);
  size_t o_x16    = align256(o_bucket + (size_t)n_dst * CAP * 4);
  const size_t x16_bytes = (size_t)n_src * DIM * 2;
  int* cnt    = (int*)(ws + o_cnt);
  uint32_t* b_tab = (uint32_t*)(ws + o_btab);
  int* bucket = (int*)(ws + o_bucket);
  uint32_t* x16 = (uint32_t*)(ws + o_x16);

  const bool use_bf16 = (ws_size >= o_x16 + x16_bytes);
  const int n4 = use_bf16 ? n_src * (DIM / 4) : 0;  // float4 units to convert

  const int convb = use_bf16 ? 1024 : 0;   // r14-proven co-residency split
  int bucketb = (n_edge + 255) / 256;
  if (bucketb < 64) bucketb = 64;  // ensure b_tab (16384 threads) covered

  hipMemsetAsync(cnt, 0, (size_t)n_dst * 4, stream);
  k1_conv_bucket<<<convb + bucketb, 256, 0, stream>>>(
      x, x16, n4, convb, src_idx, dst_idx, cnt, bucket, n_edge, W1, W2, b_tab);
  if (use_bf16) {
    fused_bf16_kernel<<<(n_dst + 63) / 64, 256, 0, stream>>>(
        (const uint16_t*)x16, cnt, bucket, degree, self_ids, b_tab, out, n_dst);
  } else {
    fused_f32_kernel<<<(n_dst + 63) / 64, 256, 0, stream>>>(
        x, cnt, bucket, degree, self_ids, b_tab, out, n_dst);
  }
}

// Round 17
// 99.854 us; speedup vs baseline: 1.0790x; 1.0319x over previous
//
#include <hip/hip_runtime.h>
#include <stdint.h>

#define DIM 128
#define CAP 32

typedef __attribute__((ext_vector_type(8))) short short8;
typedef __attribute__((ext_vector_type(4))) float f32x4;
typedef __attribute__((ext_vector_type(4))) uint32_t u32x4;

static __device__ __forceinline__ uint16_t f2bf(float f) {
  uint32_t u = __builtin_bit_cast(uint32_t, f);
  uint32_t r = (u + 0x7fffu + ((u >> 16) & 1u)) >> 16;  // RNE
  return (uint16_t)r;
}
static __device__ __forceinline__ uint32_t pack2(float a, float b) {
  return (uint32_t)f2bf(a) | ((uint32_t)f2bf(b) << 16);
}
static __device__ __forceinline__ float bflo(uint32_t u) {
  return __builtin_bit_cast(float, (uint32_t)(u << 16));
}
static __device__ __forceinline__ float bfhi(uint32_t u) {
  return __builtin_bit_cast(float, (uint32_t)(u & 0xffff0000u));
}

// ---- inline-asm memory primitives (named regs can't be sunk to scratch) ----
#define GLD4(dstv, ptr) \
  asm volatile("global_load_dwordx4 %0, %1, off" : "=&v"(dstv) : "v"(ptr))
#define VMWAIT(N)                                          \
  asm volatile("s_waitcnt vmcnt(" #N ")" ::: "memory");    \
  __builtin_amdgcn_sched_barrier(0)

// conv worker: x[f32] -> x16[bf16]. Wave-tile form: per iter a wave loads 128
// consecutive float4 (2 unit-stride GLD4/lane), packs, shfl_xor(1) pair-
// combines, and stores 64 uint4 (ONE 16B store/lane, contiguous 1KB/instr).
// Unit-stride on BOTH sides — the one combination prior rounds never ran
// (r8-11: 16B stores + strided loads; r12-16: unit loads + 8B stores).
static __device__ __forceinline__ void conv_range(
    const float* __restrict__ x, uint32_t* __restrict__ x16,
    int n4, int wid, int nw, int lane) {
  const float4* xp = reinterpret_cast<const float4*>(x);
  uint4* oq = reinterpret_cast<uint4*>(x16);
  const int ntiles = n4 >> 7;  // 128 float4 per wave-tile
  for (int T = wid; T < ntiles; T += nw) {
    const int W = T << 7;
    f32x4 vA, vB;
    GLD4(vA, xp + W + lane);
    GLD4(vB, xp + W + 64 + lane);
    VMWAIT(0);
    const uint32_t pAx = pack2(vA[0], vA[1]), pAy = pack2(vA[2], vA[3]);
    const uint32_t pBx = pack2(vB[0], vB[1]), pBy = pack2(vB[2], vB[3]);
    const uint32_t oAx = __shfl(pAx, lane ^ 1);
    const uint32_t oAy = __shfl(pAy, lane ^ 1);
    const uint32_t oBx = __shfl(pBx, lane ^ 1);
    const uint32_t oBy = __shfl(pBy, lane ^ 1);
    uint4 o;
    int idx;
    if ((lane & 1) == 0) {
      // output j = W/2 + lane/2 covers float4 (W+lane, W+lane+1)
      o.x = pAx; o.y = pAy; o.z = oAx; o.w = oAy;
      idx = (W >> 1) + (lane >> 1);
    } else {
      // output j = W/2 + 32 + lane/2 covers float4 (W+64+lane-1, W+64+lane)
      o.x = oBx; o.y = oBy; o.z = pBx; o.w = pBy;
      idx = (W >> 1) + 32 + (lane >> 1);
    }
    oq[idx] = o;
  }
  // tail (n4 % 128): scalar uint2 path, handled by the first waves
  const int tbase = ntiles << 7;
  uint2* op = reinterpret_cast<uint2*>(x16);
  for (int i = tbase + wid * 64 + lane; i < n4; i += nw * 64) {
    const float4 v = xp[i];
    uint2 t;
    t.x = pack2(v.x, v.y);
    t.y = pack2(v.z, v.w);
    op[i] = t;
  }
}

// ---- K1: conv (blocks [0,convb)) ∥ bucket scatter + B-table ----------------
__global__ __launch_bounds__(256) void k1_conv_bucket(
    const float* __restrict__ x, uint32_t* __restrict__ x16, int n4, int convb,
    const int* __restrict__ src, const int* __restrict__ dst,
    int* __restrict__ cnt, int* __restrict__ bucket, int n_edge,
    const float* __restrict__ W1, const float* __restrict__ W2,
    uint32_t* __restrict__ b_tab) {
  if ((int)blockIdx.x < convb) {
    const int lane = threadIdx.x & 63;
    const int wid = ((int)blockIdx.x << 2) | (threadIdx.x >> 6);
    conv_range(x, x16, n4, wid, convb << 2, lane);
    return;
  }
  const int gid = ((int)blockIdx.x - convb) * 256 + threadIdx.x;
  if (gid < 16384) {
    // frag(kst,ct): lane ln, elems j,j+1 -> B[k=kst*32+(ln>>4)*8+j][c=ct*16+(ln&15)]
    const int e = gid << 1;
    const int kst = e >> 12;
    const int ct  = (e >> 9) & 7;
    const int ln  = (e >> 3) & 63;
    const int j   = e & 7;
    const int k   = kst * 32 + ((ln >> 4) << 3) + j;
    const int c   = ct * 16 + (ln & 15);
    const float* wp = (k < 128) ? (W1 + c * 128 + k) : (W2 + c * 128 + (k - 128));
    b_tab[gid] = pack2(wp[0], wp[1]);
  }
  if (gid < n_edge) {
    const int d = dst[gid];
    const int c = atomicAdd(&cnt[d], 1);
    if (c < CAP) bucket[(size_t)d * CAP + c] = src[gid];
  }
}

// Per-edge id lookup from preloaded bucket registers. j is group-uniform.
#define EDGE_SID(J, OUT)                                                    \
  {                                                                         \
    const int _j = (J);                                                     \
    const int _rr = (_j >= b1) + (_j >= b2) + (_j >= b3);                   \
    const int _bs = (_rr == 0) ? 0 : (_rr == 1) ? b1 : (_rr == 2) ? b2 : b3;\
    const int _s = _j - _bs;                                                \
    const int _hi = _s >> 4;                                                \
    const int _v = (_rr == 0) ? (_hi ? idB0 : idA0)                         \
                 : (_rr == 1) ? (_hi ? idB1 : idA1)                         \
                 : (_rr == 2) ? (_hi ? idB2 : idA2)                         \
                 : (_hi ? idB3 : idA3);                                     \
    const int _sid = __shfl(_v, g16 + (_s & 15));                           \
    OUT = (_j < P) ? _sid : 0;                                              \
  }

// ---------------- Fused aggregate + GEMM, bf16 gather, bucket CSR -----------
__global__ __launch_bounds__(256, 4) void fused_bf16_kernel(
    const uint16_t* __restrict__ x16, const int* __restrict__ cnt,
    const int* __restrict__ bucket, const float* __restrict__ degree,
    const int* __restrict__ self_ids, const uint32_t* __restrict__ b_tab,
    float* __restrict__ out, int n_dst)
{
  __shared__ uint32_t As[4][16][132];   // per-wave tiles, stride 528B
  const int tid = threadIdx.x;
  const int w = tid >> 6, lane = tid & 63;
  const int g = lane >> 4, li = lane & 15;
  const int g16 = g << 4, g4 = g << 2, li8 = li << 3;
  const int rbase = blockIdx.x * 64 + w * 16;

  int cnt_all = 0, sid_all = 0;
  float deg_all = 1.f;
  if (lane < 16) {
    const int r = rbase + lane;
    const int rc = (r < n_dst) ? r : 0;
    sid_all = self_ids[rc];
    deg_all = degree[rc];
    int c = cnt[rc];
    c = c > CAP ? CAP : c;
    cnt_all = (r < n_dst) ? c : 0;
  }
  const int c0 = __shfl(cnt_all, g4 + 0);
  const int c1 = __shfl(cnt_all, g4 + 1);
  const int c2 = __shfl(cnt_all, g4 + 2);
  const int c3 = __shfl(cnt_all, g4 + 3);
  const int b1 = c0, b2 = c0 + c1, b3 = b2 + c2;
  const int P = b3 + c3;
  const float inv0 = 1.0f / __shfl(deg_all, g4 + 0);
  const float inv1 = 1.0f / __shfl(deg_all, g4 + 1);
  const float inv2 = 1.0f / __shfl(deg_all, g4 + 2);
  const float inv3 = 1.0f / __shfl(deg_all, g4 + 3);
  const int sid0 = __shfl(sid_all, g4 + 0);
  const int sid1 = __shfl(sid_all, g4 + 1);
  const int sid2 = __shfl(sid_all, g4 + 2);
  const int sid3 = __shfl(sid_all, g4 + 3);

  const int r0c = (rbase + g4 + 0 < n_dst) ? rbase + g4 + 0 : 0;
  const int r1c = (rbase + g4 + 1 < n_dst) ? rbase + g4 + 1 : 0;
  const int r2c = (rbase + g4 + 2 < n_dst) ? rbase + g4 + 2 : 0;
  const int r3c = (rbase + g4 + 3 < n_dst) ? rbase + g4 + 3 : 0;
  const int idA0 = bucket[(size_t)r0c * CAP + li];
  const int idA1 = bucket[(size_t)r1c * CAP + li];
  const int idA2 = bucket[(size_t)r2c * CAP + li];
  const int idA3 = bucket[(size_t)r3c * CAP + li];
  const int idB0 = (c0 > 16) ? bucket[(size_t)r0c * CAP + 16 + li] : 0;
  const int idB1 = (c1 > 16) ? bucket[(size_t)r1c * CAP + 16 + li] : 0;
  const int idB2 = (c2 > 16) ? bucket[(size_t)r2c * CAP + 16 + li] : 0;
  const int idB3 = (c3 > 16) ? bucket[(size_t)r3c * CAP + 16 + li] : 0;

  float a0 = 0.f, a1 = 0.f, a2 = 0.f, a3 = 0.f;
  float a4 = 0.f, a5 = 0.f, a6 = 0.f, a7 = 0.f;
  int rcur = 0;

#define FLUSH1                                                              \
  {                                                                         \
    const float _iv = (rcur == 0) ? inv0 : (rcur == 1) ? inv1               \
                    : (rcur == 2) ? inv2 : inv3;                            \
    uint4 _pa;                                                              \
    _pa.x = pack2(a0 * _iv, a1 * _iv);                                      \
    _pa.y = pack2(a2 * _iv, a3 * _iv);                                      \
    _pa.z = pack2(a4 * _iv, a5 * _iv);                                      \
    _pa.w = pack2(a6 * _iv, a7 * _iv);                                      \
    *reinterpret_cast<uint4*>(&As[w][g4 + rcur][li * 4]) = _pa;             \
    a0 = a1 = a2 = a3 = a4 = a5 = a6 = a7 = 0.f;                            \
    ++rcur;                                                                 \
  }

#define ISSUE4E(Va, Vb, Vc, Vd, E0)                                         \
  {                                                                         \
    int _sa, _sb, _sc, _sd;                                                 \
    EDGE_SID((E0) + 0, _sa);                                                \
    EDGE_SID((E0) + 1, _sb);                                                \
    EDGE_SID((E0) + 2, _sc);                                                \
    EDGE_SID((E0) + 3, _sd);                                                \
    GLD4(Va, x16 + (size_t)_sa * DIM + li8);                                \
    GLD4(Vb, x16 + (size_t)_sb * DIM + li8);                                \
    GLD4(Vc, x16 + (size_t)_sc * DIM + li8);                                \
    GLD4(Vd, x16 + (size_t)_sd * DIM + li8);                                \
  }

#define CONSUME1(V, J)                                                      \
  if ((J) < P) {                                                            \
    while (rcur < 3 &&                                                      \
           (J) >= ((rcur == 0) ? b1 : (rcur == 1) ? b2 : b3)) FLUSH1;       \
    a0 += bflo(V[0]); a1 += bfhi(V[0]);                                     \
    a2 += bflo(V[1]); a3 += bfhi(V[1]);                                     \
    a4 += bflo(V[2]); a5 += bfhi(V[2]);                                     \
    a6 += bflo(V[3]); a7 += bfhi(V[3]);                                     \
  }

  {
    u32x4 A0, A1, A2, A3, B0, B1, B2, B3;
    if (P > 0) {
      ISSUE4E(A0, A1, A2, A3, 0);
      int q = 0;
      for (;;) {
        if (q + 4 < P) {
          ISSUE4E(B0, B1, B2, B3, q + 4);
          VMWAIT(4);
        } else {
          VMWAIT(0);
        }
        CONSUME1(A0, q);
        CONSUME1(A1, q + 1);
        CONSUME1(A2, q + 2);
        CONSUME1(A3, q + 3);
        q += 4;
        if (q >= P) break;
        if (q + 4 < P) {
          ISSUE4E(A0, A1, A2, A3, q + 4);
          VMWAIT(4);
        } else {
          VMWAIT(0);
        }
        CONSUME1(B0, q);
        CONSUME1(B1, q + 1);
        CONSUME1(B2, q + 2);
        CONSUME1(B3, q + 3);
        q += 4;
        if (q >= P) break;
      }
    }
    while (rcur < 4) FLUSH1;
  }

  // Self rows (K=128..255): x16 already bf16 -> direct copy.
  {
    const uint4 sv0 = *reinterpret_cast<const uint4*>(x16 + (size_t)sid0 * DIM + li8);
    const uint4 sv1 = *reinterpret_cast<const uint4*>(x16 + (size_t)sid1 * DIM + li8);
    const uint4 sv2 = *reinterpret_cast<const uint4*>(x16 + (size_t)sid2 * DIM + li8);
    const uint4 sv3 = *reinterpret_cast<const uint4*>(x16 + (size_t)sid3 * DIM + li8);
    *reinterpret_cast<uint4*>(&As[w][g4 + 0][64 + li * 4]) = sv0;
    *reinterpret_cast<uint4*>(&As[w][g4 + 1][64 + li * 4]) = sv1;
    *reinterpret_cast<uint4*>(&As[w][g4 + 2][64 + li * 4]) = sv2;
    *reinterpret_cast<uint4*>(&As[w][g4 + 3][64 + li * 4]) = sv3;
  }

  // Phase B: A-frag lane ln holds A[row=ln&15][k=kst*32+(ln>>4)*8+j], j=0..7.
  const uint32_t* Arow = &As[w][lane & 15][(lane >> 4) << 2];
  const uint16_t* Bt = (const uint16_t*)b_tab;
  f32x4 acc[8] = {};
#pragma unroll
  for (int kst = 0; kst < 8; ++kst) {
    const short8 av = *reinterpret_cast<const short8*>(Arow + kst * 16);
#pragma unroll
    for (int ct = 0; ct < 8; ++ct) {
      const short8 bv = *reinterpret_cast<const short8*>(Bt + (kst * 8 + ct) * 512 + lane * 8);
      acc[ct] = __builtin_amdgcn_mfma_f32_16x16x32_bf16(av, bv, acc[ct], 0, 0, 0);
    }
  }

  // C/D (m89): col = lane&15, row = (lane>>4)*4 + reg.
  const int rout = rbase + ((lane >> 4) << 2);
  const int ccol = lane & 15;
#pragma unroll
  for (int ct = 0; ct < 8; ++ct) {
#pragma unroll
    for (int j = 0; j < 4; ++j) {
      const int row = rout + j;
      if (row < n_dst) out[(size_t)row * DIM + ct * 16 + ccol] = acc[ct][j];
    }
  }
#undef FLUSH1
#undef ISSUE4E
#undef CONSUME1
}

// ---------------- Fallback: f32 gather, bucket CSR (ws too small for x16) ---
__global__ __launch_bounds__(256, 4) void fused_f32_kernel(
    const float* __restrict__ x, const int* __restrict__ cnt,
    const int* __restrict__ bucket, const float* __restrict__ degree,
    const int* __restrict__ self_ids, const uint32_t* __restrict__ b_tab,
    float* __restrict__ out, int n_dst)
{
  __shared__ uint32_t As[4][16][132];
  const int tid = threadIdx.x;
  const int w = tid >> 6, lane = tid & 63;
  const int g = lane >> 4, li = lane & 15;
  const int g16 = g << 4, g4 = g << 2, li8 = li << 3;
  const int rbase = blockIdx.x * 64 + w * 16;

  int cnt_all = 0, sid_all = 0;
  float deg_all = 1.f;
  if (lane < 16) {
    const int r = rbase + lane;
    const int rc = (r < n_dst) ? r : 0;
    sid_all = self_ids[rc];
    deg_all = degree[rc];
    int c = cnt[rc];
    c = c > CAP ? CAP : c;
    cnt_all = (r < n_dst) ? c : 0;
  }
  const int c0 = __shfl(cnt_all, g4 + 0);
  const int c1 = __shfl(cnt_all, g4 + 1);
  const int c2 = __shfl(cnt_all, g4 + 2);
  const int c3 = __shfl(cnt_all, g4 + 3);
  const int b1 = c0, b2 = c0 + c1, b3 = b2 + c2;
  const int P = b3 + c3;
  const float inv0 = 1.0f / __shfl(deg_all, g4 + 0);
  const float inv1 = 1.0f / __shfl(deg_all, g4 + 1);
  const float inv2 = 1.0f / __shfl(deg_all, g4 + 2);
  const float inv3 = 1.0f / __shfl(deg_all, g4 + 3);
  const int sid0 = __shfl(sid_all, g4 + 0);
  const int sid1 = __shfl(sid_all, g4 + 1);
  const int sid2 = __shfl(sid_all, g4 + 2);
  const int sid3 = __shfl(sid_all, g4 + 3);

  const int r0c = (rbase + g4 + 0 < n_dst) ? rbase + g4 + 0 : 0;
  const int r1c = (rbase + g4 + 1 < n_dst) ? rbase + g4 + 1 : 0;
  const int r2c = (rbase + g4 + 2 < n_dst) ? rbase + g4 + 2 : 0;
  const int r3c = (rbase + g4 + 3 < n_dst) ? rbase + g4 + 3 : 0;
  const int idA0 = bucket[(size_t)r0c * CAP + li];
  const int idA1 = bucket[(size_t)r1c * CAP + li];
  const int idA2 = bucket[(size_t)r2c * CAP + li];
  const int idA3 = bucket[(size_t)r3c * CAP + li];
  const int idB0 = (c0 > 16) ? bucket[(size_t)r0c * CAP + 16 + li] : 0;
  const int idB1 = (c1 > 16) ? bucket[(size_t)r1c * CAP + 16 + li] : 0;
  const int idB2 = (c2 > 16) ? bucket[(size_t)r2c * CAP + 16 + li] : 0;
  const int idB3 = (c3 > 16) ? bucket[(size_t)r3c * CAP + 16 + li] : 0;

  float a0 = 0.f, a1 = 0.f, a2 = 0.f, a3 = 0.f;
  float a4 = 0.f, a5 = 0.f, a6 = 0.f, a7 = 0.f;
  int rcur = 0;

#define FLUSH1F                                                             \
  {                                                                         \
    const float _iv = (rcur == 0) ? inv0 : (rcur == 1) ? inv1               \
                    : (rcur == 2) ? inv2 : inv3;                            \
    uint4 _pa;                                                              \
    _pa.x = pack2(a0 * _iv, a1 * _iv);                                      \
    _pa.y = pack2(a2 * _iv, a3 * _iv);                                      \
    _pa.z = pack2(a4 * _iv, a5 * _iv);                                      \
    _pa.w = pack2(a6 * _iv, a7 * _iv);                                      \
    *reinterpret_cast<uint4*>(&As[w][g4 + rcur][li * 4]) = _pa;             \
    a0 = a1 = a2 = a3 = a4 = a5 = a6 = a7 = 0.f;                            \
    ++rcur;                                                                 \
  }

#define ISSUE2F(Va, Vb, Vc, Vd, E0)                                         \
  {                                                                         \
    int _sa, _sb;                                                           \
    EDGE_SID((E0) + 0, _sa);                                                \
    EDGE_SID((E0) + 1, _sb);                                                \
    const float* _p0 = x + (size_t)_sa * DIM + li8;                         \
    const float* _p1 = x + (size_t)_sb * DIM + li8;                         \
    GLD4(Va, _p0); GLD4(Vb, _p0 + 4);                                       \
    GLD4(Vc, _p1); GLD4(Vd, _p1 + 4);                                       \
  }

#define CONSUME_EF(Va, Vb, J)                                               \
  if ((J) < P) {                                                            \
    while (rcur < 3 &&                                                      \
           (J) >= ((rcur == 0) ? b1 : (rcur == 1) ? b2 : b3)) FLUSH1F;      \
    a0 += Va[0]; a1 += Va[1]; a2 += Va[2]; a3 += Va[3];                     \
    a4 += Vb[0]; a5 += Vb[1]; a6 += Vb[2]; a7 += Vb[3];                     \
  }

  {
    f32x4 A0, A1, A2, A3, B0, B1, B2, B3;
    if (P > 0) {
      ISSUE2F(A0, A1, A2, A3, 0);
      int q = 0;
      for (;;) {
        if (q + 2 < P) {
          ISSUE2F(B0, B1, B2, B3, q + 2);
          VMWAIT(4);
        } else {
          VMWAIT(0);
        }
        CONSUME_EF(A0, A1, q);
        CONSUME_EF(A2, A3, q + 1);
        q += 2;
        if (q >= P) break;
        if (q + 2 < P) {
          ISSUE2F(A0, A1, A2, A3, q + 2);
          VMWAIT(4);
        } else {
          VMWAIT(0);
        }
        CONSUME_EF(B0, B1, q);
        CONSUME_EF(B2, B3, q + 1);
        q += 2;
        if (q >= P) break;
      }
    }
    while (rcur < 4) FLUSH1F;
  }

  {
    const int sids[4] = {sid0, sid1, sid2, sid3};
#pragma unroll
    for (int r = 0; r < 4; ++r) {
      const float4* xs = reinterpret_cast<const float4*>(x + (size_t)sids[r] * DIM + li8);
      const float4 t0 = xs[0], t1 = xs[1];
      uint4 ps;
      ps.x = pack2(t0.x, t0.y);
      ps.y = pack2(t0.z, t0.w);
      ps.z = pack2(t1.x, t1.y);
      ps.w = pack2(t1.z, t1.w);
      *reinterpret_cast<uint4*>(&As[w][g4 + r][64 + li * 4]) = ps;
    }
  }

  const uint32_t* Arow = &As[w][lane & 15][(lane >> 4) << 2];
  const uint16_t* Bt = (const uint16_t*)b_tab;
  f32x4 acc[8] = {};
#pragma unroll
  for (int kst = 0; kst < 8; ++kst) {
    const short8 av = *reinterpret_cast<const short8*>(Arow + kst * 16);
#pragma unroll
    for (int ct = 0; ct < 8; ++ct) {
      const short8 bv = *reinterpret_cast<const short8*>(Bt + (kst * 8 + ct) * 512 + lane * 8);
      acc[ct] = __builtin_amdgcn_mfma_f32_16x16x32_bf16(av, bv, acc[ct], 0, 0, 0);
    }
  }

  const int rout = rbase + ((lane >> 4) << 2);
  const int ccol = lane & 15;
#pragma unroll
  for (int ct = 0; ct < 8; ++ct) {
#pragma unroll
    for (int j = 0; j < 4; ++j) {
      const int row = rout + j;
      if (row < n_dst) out[(size_t)row * DIM + ct * 16 + ccol] = acc[ct][j];
    }
  }
#undef FLUSH1F
#undef ISSUE2F
#undef CONSUME_EF
}

extern "C" void kernel_launch(void* const* d_in, const int* in_sizes, int n_in,
                              void* d_out, int out_size, void* d_ws, size_t ws_size,
                              hipStream_t stream) {
  const float* x        = (const float*)d_in[0];
  const float* W1       = (const float*)d_in[1];
  const float* W2       = (const float*)d_in[2];
  const float* degree   = (const float*)d_in[3];
  const int*   src_idx  = (const int*)d_in[4];
  const int*   dst_idx  = (const int*)d_in[5];
  const int*   self_ids = (const int*)d_in[6];
  float* out = (float*)d_out;
  const int n_dst  = in_sizes[3];
  const int n_edge = in_sizes[4];
  const int n_src  = in_sizes[0] / DIM;

  // ws: cnt | b_tab | bucket(n_dst*CAP) | x16(51MB, optional)
  auto align256 = [](size_t v) { return (v + 255) & ~(size_t)255; };
  char* ws = (char*)d_ws;
  size_t o_cnt    = 0;
  size_t o_btab   = align256(o_cnt + (size_t)n_dst * 4);
  size_t o_bucket = align256(o_btab + 16384 * 4);
  size_t o_x16    = align256(o_bucket + (size_t)n_dst * CAP * 4);
  const size_t x16_bytes = (size_t)n_src * DIM * 2;
  int* cnt    = (int*)(ws + o_cnt);
  uint32_t* b_tab = (uint32_t*)(ws + o_btab);
  int* bucket = (int*)(ws + o_bucket);
  uint32_t* x16 = (uint32_t*)(ws + o_x16);

  const bool use_bf16 = (ws_size >= o_x16 + x16_bytes);
  const int n4 = use_bf16 ? n_src * (DIM / 4) : 0;  // float4 units to convert

  const int convb = use_bf16 ? 1024 : 0;   // r14/r16-proven co-residency split
  int bucketb = (n_edge + 255) / 256;
  if (bucketb < 64) bucketb = 64;  // ensure b_tab (16384 threads) covered

  hipMemsetAsync(cnt, 0, (size_t)n_dst * 4, stream);
  k1_conv_bucket<<<convb + bucketb, 256, 0, stream>>>(
      x, x16, n4, convb, src_idx, dst_idx, cnt, bucket, n_edge, W1, W2, b_tab);
  if (use_bf16) {
    fused_bf16_kernel<<<(n_dst + 63) / 64, 256, 0, stream>>>(
        (const uint16_t*)x16, cnt, bucket, degree, self_ids, b_tab, out, n_dst);
  } else {
    fused_f32_kernel<<<(n_dst + 63) / 64, 256, 0, stream>>>(
        x, cnt, bucket, degree, self_ids, b_tab, out, n_dst);
  }
}